// Round 3
// baseline (808.953 us; speedup 1.0000x reference)
//
#include <hip/hip_runtime.h>

#define TT 100
#define DD 100
#define DC 25      // DD/4
#define PP 10
#define BBATCH 256
#define OC 80
#define NW 8       // waves per block (512 threads)

typedef float v2f __attribute__((ext_vector_type(2)));
typedef float v4f __attribute__((ext_vector_type(4)));

static constexpr float FEPS = 1e-6f;

template<int N> struct IC { static constexpr int v = N; };

__device__ __forceinline__ int   f2i(float x) { return __builtin_bit_cast(int, x); }
__device__ __forceinline__ float i2f(int x)   { return __builtin_bit_cast(float, x); }

// DPP row_ror:n within 16-lane rows — VALU pipe, no LDS traffic.
#define ROR_F(v, ctrl) i2f(__builtin_amdgcn_update_dpp(0, f2i(v), (ctrl), 0xf, 0xf, false))
#define ROR_I(v, ctrl) __builtin_amdgcn_update_dpp(0, (v), (ctrl), 0xf, 0xf, false)

__device__ __forceinline__ v2f xswap32_f(float v) {
#if __has_builtin(__builtin_amdgcn_permlane32_swap)
  auto pr = __builtin_amdgcn_permlane32_swap((unsigned)f2i(v), (unsigned)f2i(v), false, false);
  v2f r; r.x = i2f((int)pr[0]); r.y = i2f((int)pr[1]);
  return r;
#else
  v2f r; r.x = v; r.y = __shfl_xor(v, 32, 64);
  return r;
#endif
}

__device__ __forceinline__ float wave_sum(float v) {
  v += ROR_F(v, 0x121);
  v += ROR_F(v, 0x122);
  v += ROR_F(v, 0x124);
  v += ROR_F(v, 0x128);
  v += i2f(__builtin_amdgcn_ds_swizzle(f2i(v), 0x401f));   // lane ^ 16
  v2f s = xswap32_f(v);                                    // lane ^ 32
  return s.x + s.y;
}

__device__ __forceinline__ float wave_max(float v) {
  v = fmaxf(v, ROR_F(v, 0x121));
  v = fmaxf(v, ROR_F(v, 0x122));
  v = fmaxf(v, ROR_F(v, 0x124));
  v = fmaxf(v, ROR_F(v, 0x128));
  v = fmaxf(v, i2f(__builtin_amdgcn_ds_swizzle(f2i(v), 0x401f)));
  v2f s = xswap32_f(v);
  return fmaxf(s.x, s.y);
}

__device__ __forceinline__ void amax2(float& v, int& i, float ov, int oi) {
  if (ov > v || (ov == v && oi < i)) { v = ov; i = oi; }
}

__device__ __forceinline__ void wave_argmax(float& v, int& idx) {
  amax2(v, idx, ROR_F(v, 0x121), ROR_I(idx, 0x121));
  amax2(v, idx, ROR_F(v, 0x122), ROR_I(idx, 0x122));
  amax2(v, idx, ROR_F(v, 0x124), ROR_I(idx, 0x124));
  amax2(v, idx, ROR_F(v, 0x128), ROR_I(idx, 0x128));
  amax2(v, idx, i2f(__builtin_amdgcn_ds_swizzle(f2i(v), 0x401f)),
        __builtin_amdgcn_ds_swizzle(idx, 0x401f));
#if __has_builtin(__builtin_amdgcn_permlane32_swap)
  {
    auto rv = __builtin_amdgcn_permlane32_swap((unsigned)f2i(v), (unsigned)f2i(v), false, false);
    auto ri = __builtin_amdgcn_permlane32_swap((unsigned)idx, (unsigned)idx, false, false);
    amax2(v, idx, i2f((int)rv[0]), (int)ri[0]);
    amax2(v, idx, i2f((int)rv[1]), (int)ri[1]);
  }
#else
  amax2(v, idx, __shfl_xor(v, 32, 64), __shfl_xor(idx, 32, 64));
#endif
}

// 512 threads = 8 waves/block; 2 blocks/CU (LDS ~80.4KB x2 = 160.7KB <= 160KB pool).
// __launch_bounds__(512,2): register cap 256 — R1 showed (512,4) forces 64 VGPR
// and spills Phase-B accumulators to scratch (4.4GB FETCH). Natural alloc ~124.
__global__ __launch_bounds__(512, 2) void match_kernel(
    const float* __restrict__ s1, const float* __restrict__ s2,
    const float* __restrict__ w1, const float* __restrict__ w2,
    const float* __restrict__ w3, const float* __restrict__ w4,
    const float* __restrict__ w5, const float* __restrict__ w6,
    const float* __restrict__ w7, const float* __restrict__ w8,
    float* __restrict__ out)
{
  const int dir  = blockIdx.x & 1;
  const int b    = blockIdx.x >> 1;
  const int doff = dir * DD;
  const int tid  = threadIdx.x;
  const int lane = tid & 63;
  const int wv   = tid >> 6;

  const float* wfull = dir ? w2 : w1;
  const float* wmax  = dir ? w4 : w3;
  const float* wmean = dir ? w6 : w5;
  const float* watt2 = dir ? w8 : w7;   // fwd: max-att (w7); bwd: mean-att (w8)

  // s2 in d-chunked layout: d = 4c+k. j-stride = 16B (b128-able, conflict-free
  // lane-over-j); chunk stride = 404 dwords == 20 mod 32 (2-way free in phase D).
  __shared__ __align__(16) float S2V[DC][TT + 1][4];
  __shared__ __align__(16) float W2SQ[PP][DD];       // p-major-row: norms (v4f over d)
  __shared__ __align__(16) float W2T[DC][4][PP];     // d-major: Phase-B p-pair v2f loads
  __shared__ float N2PI[TT];
  __shared__ float N2WI[TT][11];        // padded: (11j+p)%32 -> 2-way free
  // Wave-private regions (wave owns rows [wv*4, wv*4+4)): no barriers needed.
  __shared__ __align__(16) float S1R[4 * NW][DD];
  __shared__ __align__(16) float CROW[4 * NW][DD];
  __shared__ float N1PI[4 * NW];
  __shared__ float N1WI[4 * NW][PP];
  __shared__ int   ARGJ[4 * NW];

  // ---- Phase 1: load s2 tile (d-chunked) + maxpool w^2 in BOTH layouts ----
  for (int idx = tid; idx < TT * DD; idx += 512) {
    int j = idx / DD, d = idx - j * DD;
    S2V[d >> 2][j][d & 3] = s2[(j * BBATCH + b) * (2 * DD) + doff + d];
  }
  for (int idx = tid; idx < PP * DD; idx += 512) {
    int p = idx / DD, d = idx - p * DD;
    float v = wmax[idx];
    float v2 = v * v;
    W2SQ[p][d] = v2;
    W2T[d >> 2][d & 3][p] = v2;
  }
  __syncthreads();

  // ---- Phase 2: s2 norms (plain + weighted rsqrt), float4 reads ----
  for (int task = tid; task < TT + TT * PP; task += 512) {
    if (task < TT) {
      int j = task;
      float a = 0.f;
      for (int c = 0; c < DC; ++c) {
        v4f f = *(const v4f*)&S2V[c][j][0];
#pragma unroll
        for (int k = 0; k < 4; ++k) a = fmaf(f[k], f[k], a);
      }
      N2PI[j] = 1.0f / sqrtf(fmaxf(a, FEPS));   // feeds argmax-sensitive cos
    } else {
      int q = task - TT; int j = q / PP, p = q - j * PP;
      float a = 0.f;
      for (int c = 0; c < DC; ++c) {
        v4f f = *(const v4f*)&S2V[c][j][0];
        v4f w = *(const v4f*)&W2SQ[p][4 * c];
#pragma unroll
        for (int k = 0; k < 4; ++k) a = fmaf(f[k] * f[k], w[k], a);
      }
      N2WI[j][p] = rsqrtf(fmaxf(a, FEPS));
    }
  }
  __syncthreads();
  // ---- After this point: ZERO barriers. Remaining LDS state is read-only
  // (S2V/W2SQ/W2T/N2*) or wave-private (S1R/CROW/N1*/ARGJ).

  const int  j0   = lane;
  const int  j1   = 64 + lane;
  const bool act1 = (j1 < TT);
  const int  j1c  = act1 ? j1 : (TT - 1);
  const bool actd = (64 + lane) < DD;
  const int  d1   = actd ? (64 + lane) : (DD - 1);
  const int  c0i  = lane >> 2, k0 = lane & 3;      // phase-D d0 = lane
  const int  c1i  = d1 >> 2,   k1 = d1 & 3;        // phase-D d1

  const int sl = wv * 4;

  // Row-group body, NR rows starting at i0. NR is compile-time via IC<> so all
  // inner loops fully unroll per instantiation (NR=4 main, NR=1 tail).
  auto body = [&](auto ic, const int i0) {
    constexpr int NR = decltype(ic)::v;

    // wave-private S1R staging: NR rows x 25 float4 chunks
    for (int q = lane; q < NR * DC; q += 64) {
      int rr = q / DC, c = q - rr * DC;
      *(v4f*)&S1R[sl + rr][4 * c] =
          *(const v4f*)&s1[((i0 + rr) * BBATCH + b) * (2 * DD) + doff + 4 * c];
    }

    // wave-private s1 norms: NR rows x (1 plain + 10 weighted)
    if (lane < NR * 11) {
      int rr = lane / 11, q = lane - rr * 11;
      if (q == 0) {
        float a = 0.f;
        for (int c = 0; c < DC; ++c) {
          v4f f = *(const v4f*)&S1R[sl + rr][4 * c];
#pragma unroll
          for (int k = 0; k < 4; ++k) a = fmaf(f[k], f[k], a);
        }
        N1PI[sl + rr] = 1.0f / sqrtf(fmaxf(a, FEPS));
      } else {
        int p = q - 1;
        float a = 0.f;
        for (int c = 0; c < DC; ++c) {
          v4f f = *(const v4f*)&S1R[sl + rr][4 * c];
          v4f w = *(const v4f*)&W2SQ[p][4 * c];
#pragma unroll
          for (int k = 0; k < 4; ++k) a = fmaf(f[k] * f[k], w[k], a);
        }
        N1WI[sl + rr][p] = rsqrtf(fmaxf(a, FEPS));
      }
    }

    // ---- Phase B: scalar dot (j0,j1) + maxpool FMAs packed over p-pairs.
    // W2T p-major v2f loads mean ZERO w-splat movs (was 20 movs/(c,k,r)).
    // Accumulation sequence per (j,p) accumulator identical to the packed-j
    // version -> bit-exact vs the passing R2 kernel.
    float dot0[NR], dot1[NR];
    v2f wap[NR][2][5];                  // [row][j0/j1][p-pair]
#pragma unroll
    for (int r = 0; r < NR; ++r) {
      dot0[r] = 0.f; dot1[r] = 0.f;
#pragma unroll
      for (int pp = 0; pp < 5; ++pp) {
        wap[r][0][pp] = (v2f){0.f, 0.f};
        wap[r][1][pp] = (v2f){0.f, 0.f};
      }
    }

    for (int c = 0; c < DC; ++c) {
      v4f s2a4 = *(const v4f*)&S2V[c][j0][0];
      v4f s2b4 = *(const v4f*)&S2V[c][j1c][0];
      v4f s1v[NR];
#pragma unroll
      for (int r = 0; r < NR; ++r) s1v[r] = *(const v4f*)&S1R[sl + r][4 * c];
#pragma unroll
      for (int k = 0; k < 4; ++k) {
        v4f wA = *(const v4f*)&W2T[c][k][0];   // p0..3 (pairs aligned)
        v4f wB = *(const v4f*)&W2T[c][k][4];   // p4..7
        v2f wC = *(const v2f*)&W2T[c][k][8];   // p8..9
        v2f wp[5];
        wp[0] = __builtin_shufflevector(wA, wA, 0, 1);
        wp[1] = __builtin_shufflevector(wA, wA, 2, 3);
        wp[2] = __builtin_shufflevector(wB, wB, 0, 1);
        wp[3] = __builtin_shufflevector(wB, wB, 2, 3);
        wp[4] = wC;
#pragma unroll
        for (int r = 0; r < NR; ++r) {
          float ta0 = s1v[r][k] * s2a4[k];     // v_mul
          float ta1 = s1v[r][k] * s2b4[k];     // v_mul
          dot0[r] += ta0;                      // v_add (same order as pk .x path)
          dot1[r] += ta1;
          v2f t0; t0.x = ta0; t0.y = ta0;      // 2 movs
          v2f t1; t1.x = ta1; t1.y = ta1;      // 2 movs
#pragma unroll
          for (int pp = 0; pp < 5; ++pp) {
            wap[r][0][pp] = __builtin_elementwise_fma(t0, wp[pp], wap[r][0][pp]);  // v_pk_fma
            wap[r][1][pp] = __builtin_elementwise_fma(t1, wp[pp], wap[r][1][pp]);
          }
        }
      }
    }

    // ---- Phase C: cos rows, rowsum, argmax, maxpool (DPP/permlane reductions) ----
    float rs[NR];
#pragma unroll
    for (int r = 0; r < NR; ++r) {
      float n1pi_r = N1PI[sl + r];
      float c0 = dot0[r] * (n1pi_r * N2PI[j0]);
      float c1 = dot1[r] * (n1pi_r * N2PI[j1c]);
      CROW[sl + r][j0] = c0;
      if (act1) CROW[sl + r][j1] = c1;
      rs[r] = wave_sum(c0 + (act1 ? c1 : 0.f));

      float mv = c0; int mi = j0;
      if (act1 && (c1 > mv)) { mv = c1; mi = j1; }
      wave_argmax(mv, mi);
      if (lane == 0) ARGJ[sl + r] = mi;

#pragma unroll
      for (int p = 0; p < PP; ++p) {
        float a0 = (p & 1) ? wap[r][0][p >> 1].y : wap[r][0][p >> 1].x;
        float a1 = (p & 1) ? wap[r][1][p >> 1].y : wap[r][1][p >> 1].x;
        float v0 = a0 * N2WI[j0][p];
        float v1 = act1 ? a1 * N2WI[j1c][p] : -3.4e38f;
        float m = wave_max(fmaxf(v0, v1));
        if (lane == 0) {
          out[((i0 + r) * BBATCH + b) * OC + 20 + dir * PP + p] = m * N1WI[sl + r][p];
        }
      }
    }

    // ---- Phase D: mean-att accumulation, scalar (d0,d1); reads own CROW rows ----
    float att0[NR], att1[NR];
#pragma unroll
    for (int r = 0; r < NR; ++r) { att0[r] = 0.f; att1[r] = 0.f; }
    for (int j = 0; j < TT; ++j) {
      float s2d0 = S2V[c0i][j][k0];
      float s2d1 = S2V[c1i][j][k1];
#pragma unroll
      for (int r = 0; r < NR; ++r) {
        float cv = CROW[sl + r][j];
        att0[r] = fmaf(cv, s2d0, att0[r]);
        att1[r] = fmaf(cv, s2d1, att1[r]);
      }
    }

    // overwrite own CROW rows with att rows (same-wave ordering suffices)
#pragma unroll
    for (int r = 0; r < NR; ++r) {
      float inv = 1.0f / (rs[r] + FEPS);
      CROW[sl + r][lane] = att0[r] * inv;
      if (actd) CROW[sl + r][64 + lane] = att1[r] * inv;
    }

    // ---- Phase E: NR*30 tasks = rows x {full, mean-att, att2} x 10 p ----
    for (int tk = lane; tk < NR * 30; tk += 64) {
      int r = tk / 30;
      int q = tk - r * 30;
      int set = q / PP;
      int p = q - set * PP;
      const float* wrow = (set == 0 ? wfull : (set == 1 ? wmean : watt2)) + p * DD;
      // reference quirk: s2.reshape(-1,D)[argmax] == s2f[0, argmax, :] (fwd only)
      const float* gat = s2 + ARGJ[sl + r] * (2 * DD);
      float num = 0.f, nx = 0.f, ny = 0.f;
      for (int c = 0; c < DC; ++c) {
        v4f x4 = *(const v4f*)&S1R[sl + r][4 * c];
        v4f y4;
        if (set == 0)                     y4 = *(const v4f*)&S2V[c][TT - 1][0];
        else if (set == 1 || dir == 1)    y4 = *(const v4f*)&CROW[sl + r][4 * c];
        else                              y4 = *(const v4f*)&gat[4 * c];
        v4f w4 = *(const v4f*)&wrow[4 * c];
#pragma unroll
        for (int k = 0; k < 4; ++k) {
          float w2v = w4[k] * w4[k];
          num = fmaf(x4[k] * y4[k], w2v, num);
          nx  = fmaf(x4[k] * x4[k], w2v, nx);
          ny  = fmaf(y4[k] * y4[k], w2v, ny);
        }
      }
      float cres = num * rsqrtf(fmaxf(nx, FEPS)) * rsqrtf(fmaxf(ny, FEPS));
      int ch = (set == 0 ? 0 : (set == 1 ? 40 : 60)) + dir * PP + p;
      out[((i0 + r) * BBATCH + b) * OC + ch] = cres;
    }
  };

  // ---- Balanced row assignment: waves 0-3 own 12 rows (3x4), waves 4-7 own
  // 13 rows (3x4 + one single-row tail pass). Old g%8 scheme gave wave0 four
  // full iterations vs three -> ~25% of block time with 1/8 waves active.
  const int start = wv * 12 + (wv > 4 ? wv - 4 : 0);
  for (int it = 0; it < 3; ++it) body(IC<4>{}, start + it * 4);
  if (wv >= 4) body(IC<1>{}, start + 12);
}

extern "C" void kernel_launch(void* const* d_in, const int* in_sizes, int n_in,
                              void* d_out, int out_size, void* d_ws, size_t ws_size,
                              hipStream_t stream) {
  const float* s1 = (const float*)d_in[0];
  const float* s2 = (const float*)d_in[1];
  match_kernel<<<dim3(512), dim3(512), 0, stream>>>(
      s1, s2,
      (const float*)d_in[2], (const float*)d_in[3],
      (const float*)d_in[4], (const float*)d_in[5],
      (const float*)d_in[6], (const float*)d_in[7],
      (const float*)d_in[8], (const float*)d_in[9],
      (float*)d_out);
}

// Round 4
// 807.091 us; speedup vs baseline: 1.0023x; 1.0023x over previous
//
#include <hip/hip_runtime.h>

#define TT 100
#define DD 100
#define DC 25      // DD/4
#define PP 10
#define BBATCH 256
#define OC 80
#define NW 8       // waves per block (512 threads)

typedef float v2f __attribute__((ext_vector_type(2)));
typedef float v4f __attribute__((ext_vector_type(4)));

static constexpr float FEPS = 1e-6f;

template<int N> struct IC { static constexpr int v = N; };

__device__ __forceinline__ int   f2i(float x) { return __builtin_bit_cast(int, x); }
__device__ __forceinline__ float i2f(int x)   { return __builtin_bit_cast(float, x); }

// DPP row_ror:n within 16-lane rows — VALU pipe, no LDS traffic.
#define ROR_F(v, ctrl) i2f(__builtin_amdgcn_update_dpp(0, f2i(v), (ctrl), 0xf, 0xf, false))
#define ROR_I(v, ctrl) __builtin_amdgcn_update_dpp(0, (v), (ctrl), 0xf, 0xf, false)

__device__ __forceinline__ v2f xswap32_f(float v) {
#if __has_builtin(__builtin_amdgcn_permlane32_swap)
  auto pr = __builtin_amdgcn_permlane32_swap((unsigned)f2i(v), (unsigned)f2i(v), false, false);
  v2f r; r.x = i2f((int)pr[0]); r.y = i2f((int)pr[1]);
  return r;
#else
  v2f r; r.x = v; r.y = __shfl_xor(v, 32, 64);
  return r;
#endif
}

__device__ __forceinline__ float wave_sum(float v) {
  v += ROR_F(v, 0x121);
  v += ROR_F(v, 0x122);
  v += ROR_F(v, 0x124);
  v += ROR_F(v, 0x128);
  v += i2f(__builtin_amdgcn_ds_swizzle(f2i(v), 0x401f));   // lane ^ 16
  v2f s = xswap32_f(v);                                    // lane ^ 32
  return s.x + s.y;
}

__device__ __forceinline__ float wave_max(float v) {
  v = fmaxf(v, ROR_F(v, 0x121));
  v = fmaxf(v, ROR_F(v, 0x122));
  v = fmaxf(v, ROR_F(v, 0x124));
  v = fmaxf(v, ROR_F(v, 0x128));
  v = fmaxf(v, i2f(__builtin_amdgcn_ds_swizzle(f2i(v), 0x401f)));
  v2f s = xswap32_f(v);
  return fmaxf(s.x, s.y);
}

__device__ __forceinline__ void amax2(float& v, int& i, float ov, int oi) {
  if (ov > v || (ov == v && oi < i)) { v = ov; i = oi; }
}

__device__ __forceinline__ void wave_argmax(float& v, int& idx) {
  amax2(v, idx, ROR_F(v, 0x121), ROR_I(idx, 0x121));
  amax2(v, idx, ROR_F(v, 0x122), ROR_I(idx, 0x122));
  amax2(v, idx, ROR_F(v, 0x124), ROR_I(idx, 0x124));
  amax2(v, idx, ROR_F(v, 0x128), ROR_I(idx, 0x128));
  amax2(v, idx, i2f(__builtin_amdgcn_ds_swizzle(f2i(v), 0x401f)),
        __builtin_amdgcn_ds_swizzle(idx, 0x401f));
#if __has_builtin(__builtin_amdgcn_permlane32_swap)
  {
    auto rv = __builtin_amdgcn_permlane32_swap((unsigned)f2i(v), (unsigned)f2i(v), false, false);
    auto ri = __builtin_amdgcn_permlane32_swap((unsigned)idx, (unsigned)idx, false, false);
    amax2(v, idx, i2f((int)rv[0]), (int)ri[0]);
    amax2(v, idx, i2f((int)rv[1]), (int)ri[1]);
  }
#else
  amax2(v, idx, __shfl_xor(v, 32, 64), __shfl_xor(idx, 32, 64));
#endif
}

// 512 threads = 8 waves/block; 2 blocks/CU (LDS 76.8KB x2 = 153.6KB <= 160KB).
// __launch_bounds__(512,2) => VGPR cap 128 (empirical: (512,4) capped at 64,
// R1 spilled; (512,2) caps at 128, R2's Phase B fits at 124, R3's repack hit
// 128+scratch). Phase B below is R2's exact form — do not restructure without
// checking -Rpass-analysis register usage first.
__global__ __launch_bounds__(512, 2) void match_kernel(
    const float* __restrict__ s1, const float* __restrict__ s2,
    const float* __restrict__ w1, const float* __restrict__ w2,
    const float* __restrict__ w3, const float* __restrict__ w4,
    const float* __restrict__ w5, const float* __restrict__ w6,
    const float* __restrict__ w7, const float* __restrict__ w8,
    float* __restrict__ out)
{
  const int dir  = blockIdx.x & 1;
  const int b    = blockIdx.x >> 1;
  const int doff = dir * DD;
  const int tid  = threadIdx.x;
  const int lane = tid & 63;
  const int wv   = tid >> 6;

  const float* wfull = dir ? w2 : w1;
  const float* wmax  = dir ? w4 : w3;
  const float* wmean = dir ? w6 : w5;
  const float* watt2 = dir ? w8 : w7;   // fwd: max-att (w7); bwd: mean-att (w8)

  // s2 in d-chunked layout: d = 4c+k. j-stride = 16B (b128-able, conflict-free
  // lane-over-j); chunk stride = 404 dwords == 20 mod 32 (2-way free in phase D).
  __shared__ __align__(16) float S2V[DC][TT + 1][4];
  __shared__ __align__(16) float W2SQ[PP][DD];
  __shared__ float N2PI[TT];
  __shared__ float N2WI[TT][11];        // padded: (11j+p)%32 -> 2-way free
  // Wave-private regions (wave owns rows [wv*4, wv*4+4)): no barriers needed.
  __shared__ __align__(16) float S1R[4 * NW][DD];
  __shared__ __align__(16) float CROW[4 * NW][DD];
  __shared__ float N1PI[4 * NW];
  __shared__ float N1WI[4 * NW][PP];
  __shared__ int   ARGJ[4 * NW];

  // ---- Phase 1: load s2 tile (d-chunked) + maxpool w^2 ----
  for (int idx = tid; idx < TT * DD; idx += 512) {
    int j = idx / DD, d = idx - j * DD;
    S2V[d >> 2][j][d & 3] = s2[(j * BBATCH + b) * (2 * DD) + doff + d];
  }
  for (int idx = tid; idx < PP * DD; idx += 512) {
    int p = idx / DD, d = idx - p * DD;
    float v = wmax[idx];
    W2SQ[p][d] = v * v;
  }
  __syncthreads();

  // ---- Phase 2: s2 norms (plain + weighted rsqrt), float4 reads ----
  for (int task = tid; task < TT + TT * PP; task += 512) {
    if (task < TT) {
      int j = task;
      float a = 0.f;
      for (int c = 0; c < DC; ++c) {
        v4f f = *(const v4f*)&S2V[c][j][0];
#pragma unroll
        for (int k = 0; k < 4; ++k) a = fmaf(f[k], f[k], a);
      }
      N2PI[j] = 1.0f / sqrtf(fmaxf(a, FEPS));   // feeds argmax-sensitive cos
    } else {
      int q = task - TT; int j = q / PP, p = q - j * PP;
      float a = 0.f;
      for (int c = 0; c < DC; ++c) {
        v4f f = *(const v4f*)&S2V[c][j][0];
        v4f w = *(const v4f*)&W2SQ[p][4 * c];
#pragma unroll
        for (int k = 0; k < 4; ++k) a = fmaf(f[k] * f[k], w[k], a);
      }
      N2WI[j][p] = rsqrtf(fmaxf(a, FEPS));
    }
  }
  __syncthreads();
  // ---- After this point: ZERO barriers. Remaining LDS state is read-only
  // (S2V/W2SQ/N2*) or wave-private (S1R/CROW/N1*/ARGJ).

  const int  j0   = lane;
  const int  j1   = 64 + lane;
  const bool act1 = (j1 < TT);
  const int  j1c  = act1 ? j1 : (TT - 1);
  const bool actd = (64 + lane) < DD;
  const int  d1   = actd ? (64 + lane) : (DD - 1);
  const int  c0i  = lane >> 2, k0 = lane & 3;      // phase-D d0 = lane
  const int  c1i  = d1 >> 2,   k1 = d1 & 3;        // phase-D d1

  const int sl = wv * 4;

  // Row-group body, NR rows starting at i0 (compile-time NR: 4 main, 1 tail).
  auto body = [&](auto ic, const int i0) {
    constexpr int NR = decltype(ic)::v;

    // wave-private S1R staging: NR rows x 25 float4 chunks
    for (int q = lane; q < NR * DC; q += 64) {
      int rr = q / DC, c = q - rr * DC;
      *(v4f*)&S1R[sl + rr][4 * c] =
          *(const v4f*)&s1[((i0 + rr) * BBATCH + b) * (2 * DD) + doff + 4 * c];
    }

    // wave-private s1 norms: NR rows x (1 plain + 10 weighted)
    if (lane < NR * 11) {
      int rr = lane / 11, q = lane - rr * 11;
      if (q == 0) {
        float a = 0.f;
        for (int c = 0; c < DC; ++c) {
          v4f f = *(const v4f*)&S1R[sl + rr][4 * c];
#pragma unroll
          for (int k = 0; k < 4; ++k) a = fmaf(f[k], f[k], a);
        }
        N1PI[sl + rr] = 1.0f / sqrtf(fmaxf(a, FEPS));
      } else {
        int p = q - 1;
        float a = 0.f;
        for (int c = 0; c < DC; ++c) {
          v4f f = *(const v4f*)&S1R[sl + rr][4 * c];
          v4f w = *(const v4f*)&W2SQ[p][4 * c];
#pragma unroll
          for (int k = 0; k < 4; ++k) a = fmaf(f[k] * f[k], w[k], a);
        }
        N1WI[sl + rr][p] = rsqrtf(fmaxf(a, FEPS));
      }
    }

    // ---- Phase B: packed (j0,j1) main dot pass, b128 LDS reads ----
    // (R2's exact form: 124 VGPR under the 128 cap. Do not repack — R3's
    // p-pair variant spilled to scratch.)
    v2f dotp[NR];
    v2f wap[NR][PP];
#pragma unroll
    for (int r = 0; r < NR; ++r) {
      dotp[r] = (v2f){0.f, 0.f};
#pragma unroll
      for (int p = 0; p < PP; ++p) wap[r][p] = (v2f){0.f, 0.f};
    }

    for (int c = 0; c < DC; ++c) {
      v4f s2a4 = *(const v4f*)&S2V[c][j0][0];
      v4f s2b4 = *(const v4f*)&S2V[c][j1c][0];
      v4f wq[PP];
#pragma unroll
      for (int p = 0; p < PP; ++p) wq[p] = *(const v4f*)&W2SQ[p][4 * c];
      v4f s1v[NR];
#pragma unroll
      for (int r = 0; r < NR; ++r) s1v[r] = *(const v4f*)&S1R[sl + r][4 * c];
#pragma unroll
      for (int k = 0; k < 4; ++k) {
        v2f s2ab; s2ab.x = s2a4[k]; s2ab.y = s2b4[k];
#pragma unroll
        for (int r = 0; r < NR; ++r) {
          v2f s1xx; s1xx.x = s1v[r][k]; s1xx.y = s1v[r][k];
          v2f ta = s1xx * s2ab;     // v_pk_mul_f32
          dotp[r] += ta;            // v_pk_add_f32
#pragma unroll
          for (int p = 0; p < PP; ++p) {
            v2f wk; wk.x = wq[p][k]; wk.y = wq[p][k];
            wap[r][p] = __builtin_elementwise_fma(ta, wk, wap[r][p]);  // v_pk_fma_f32
          }
        }
      }
    }

    // ---- Phase C: cos rows, rowsum, argmax, maxpool (DPP/permlane reductions) ----
    float rs[NR];
#pragma unroll
    for (int r = 0; r < NR; ++r) {
      float n1pi_r = N1PI[sl + r];
      float c0 = dotp[r].x * (n1pi_r * N2PI[j0]);
      float c1 = dotp[r].y * (n1pi_r * N2PI[j1c]);
      CROW[sl + r][j0] = c0;
      if (act1) CROW[sl + r][j1] = c1;
      rs[r] = wave_sum(c0 + (act1 ? c1 : 0.f));

      float mv = c0; int mi = j0;
      if (act1 && (c1 > mv)) { mv = c1; mi = j1; }
      wave_argmax(mv, mi);
      if (lane == 0) ARGJ[sl + r] = mi;

#pragma unroll
      for (int p = 0; p < PP; ++p) {
        float v0 = wap[r][p].x * N2WI[j0][p];
        float v1 = act1 ? wap[r][p].y * N2WI[j1c][p] : -3.4e38f;
        float m = wave_max(fmaxf(v0, v1));
        if (lane == 0) {
          out[((i0 + r) * BBATCH + b) * OC + 20 + dir * PP + p] = m * N1WI[sl + r][p];
        }
      }
    }

    // ---- Phase D: mean-att accumulation, scalar (d0,d1); reads own CROW rows.
    // Scalar form: 2*NR fmas/j vs packed's NR pk_fma + 2*NR splat movs — fewer
    // issue slots, identical rounding, identical register count.
    float att0[NR], att1[NR];
#pragma unroll
    for (int r = 0; r < NR; ++r) { att0[r] = 0.f; att1[r] = 0.f; }
    for (int j = 0; j < TT; ++j) {
      float s2d0 = S2V[c0i][j][k0];
      float s2d1 = S2V[c1i][j][k1];
#pragma unroll
      for (int r = 0; r < NR; ++r) {
        float cv = CROW[sl + r][j];
        att0[r] = fmaf(cv, s2d0, att0[r]);
        att1[r] = fmaf(cv, s2d1, att1[r]);
      }
    }

    // overwrite own CROW rows with att rows (same-wave ordering suffices)
#pragma unroll
    for (int r = 0; r < NR; ++r) {
      float inv = 1.0f / (rs[r] + FEPS);
      CROW[sl + r][lane] = att0[r] * inv;
      if (actd) CROW[sl + r][64 + lane] = att1[r] * inv;
    }

    // ---- Phase E: NR*30 tasks = rows x {full, mean-att, att2} x 10 p ----
    for (int tk = lane; tk < NR * 30; tk += 64) {
      int r = tk / 30;
      int q = tk - r * 30;
      int set = q / PP;
      int p = q - set * PP;
      const float* wrow = (set == 0 ? wfull : (set == 1 ? wmean : watt2)) + p * DD;
      // reference quirk: s2.reshape(-1,D)[argmax] == s2f[0, argmax, :] (fwd only)
      const float* gat = s2 + ARGJ[sl + r] * (2 * DD);
      float num = 0.f, nx = 0.f, ny = 0.f;
      for (int c = 0; c < DC; ++c) {
        v4f x4 = *(const v4f*)&S1R[sl + r][4 * c];
        v4f y4;
        if (set == 0)                     y4 = *(const v4f*)&S2V[c][TT - 1][0];
        else if (set == 1 || dir == 1)    y4 = *(const v4f*)&CROW[sl + r][4 * c];
        else                              y4 = *(const v4f*)&gat[4 * c];
        v4f w4 = *(const v4f*)&wrow[4 * c];
#pragma unroll
        for (int k = 0; k < 4; ++k) {
          float w2v = w4[k] * w4[k];
          num = fmaf(x4[k] * y4[k], w2v, num);
          nx  = fmaf(x4[k] * x4[k], w2v, nx);
          ny  = fmaf(y4[k] * y4[k], w2v, ny);
        }
      }
      float cres = num * rsqrtf(fmaxf(nx, FEPS)) * rsqrtf(fmaxf(ny, FEPS));
      int ch = (set == 0 ? 0 : (set == 1 ? 40 : 60)) + dir * PP + p;
      out[((i0 + r) * BBATCH + b) * OC + ch] = cres;
    }
  };

  // ---- Balanced row assignment (validated in R3): waves 0-3 own 12 rows
  // (3x NR=4), waves 4-7 own 13 (3x NR=4 + one NR=1 tail). Coverage:
  // w0:0-11 w1:12-23 w2:24-35 w3:36-47 w4:48-60 w5:61-73 w6:74-86 w7:87-99.
  const int start = wv * 12 + (wv > 4 ? wv - 4 : 0);
  for (int it = 0; it < 3; ++it) body(IC<4>{}, start + it * 4);
  if (wv >= 4) body(IC<1>{}, start + 12);
}

extern "C" void kernel_launch(void* const* d_in, const int* in_sizes, int n_in,
                              void* d_out, int out_size, void* d_ws, size_t ws_size,
                              hipStream_t stream) {
  const float* s1 = (const float*)d_in[0];
  const float* s2 = (const float*)d_in[1];
  match_kernel<<<dim3(512), dim3(512), 0, stream>>>(
      s1, s2,
      (const float*)d_in[2], (const float*)d_in[3],
      (const float*)d_in[4], (const float*)d_in[5],
      (const float*)d_in[6], (const float*)d_in[7],
      (const float*)d_in[8], (const float*)d_in[9],
      (float*)d_out);
}

// Round 5
// 417.991 us; speedup vs baseline: 1.9353x; 1.9309x over previous
//
#include <hip/hip_runtime.h>

#define TT 100
#define DD 100
#define DC 25      // DD/4
#define PP 10
#define BBATCH 256
#define OC 80
#define NW 8       // waves per block (512 threads)

typedef float v2f __attribute__((ext_vector_type(2)));
typedef float v4f __attribute__((ext_vector_type(4)));

static constexpr float FEPS = 1e-6f;

__device__ __forceinline__ int   f2i(float x) { return __builtin_bit_cast(int, x); }
__device__ __forceinline__ float i2f(int x)   { return __builtin_bit_cast(float, x); }

// DPP row_ror:n within 16-lane rows — VALU pipe, no LDS traffic.
#define ROR_F(v, ctrl) i2f(__builtin_amdgcn_update_dpp(0, f2i(v), (ctrl), 0xf, 0xf, false))
#define ROR_I(v, ctrl) __builtin_amdgcn_update_dpp(0, (v), (ctrl), 0xf, 0xf, false)

__device__ __forceinline__ v2f xswap32_f(float v) {
#if __has_builtin(__builtin_amdgcn_permlane32_swap)
  auto pr = __builtin_amdgcn_permlane32_swap((unsigned)f2i(v), (unsigned)f2i(v), false, false);
  v2f r; r.x = i2f((int)pr[0]); r.y = i2f((int)pr[1]);
  return r;
#else
  v2f r; r.x = v; r.y = __shfl_xor(v, 32, 64);
  return r;
#endif
}

__device__ __forceinline__ float wave_sum(float v) {
  v += ROR_F(v, 0x121);
  v += ROR_F(v, 0x122);
  v += ROR_F(v, 0x124);
  v += ROR_F(v, 0x128);
  v += i2f(__builtin_amdgcn_ds_swizzle(f2i(v), 0x401f));   // lane ^ 16
  v2f s = xswap32_f(v);                                    // lane ^ 32
  return s.x + s.y;
}

__device__ __forceinline__ float wave_max(float v) {
  v = fmaxf(v, ROR_F(v, 0x121));
  v = fmaxf(v, ROR_F(v, 0x122));
  v = fmaxf(v, ROR_F(v, 0x124));
  v = fmaxf(v, ROR_F(v, 0x128));
  v = fmaxf(v, i2f(__builtin_amdgcn_ds_swizzle(f2i(v), 0x401f)));
  v2f s = xswap32_f(v);
  return fmaxf(s.x, s.y);
}

__device__ __forceinline__ void amax2(float& v, int& i, float ov, int oi) {
  if (ov > v || (ov == v && oi < i)) { v = ov; i = oi; }
}

__device__ __forceinline__ void wave_argmax(float& v, int& idx) {
  amax2(v, idx, ROR_F(v, 0x121), ROR_I(idx, 0x121));
  amax2(v, idx, ROR_F(v, 0x122), ROR_I(idx, 0x122));
  amax2(v, idx, ROR_F(v, 0x124), ROR_I(idx, 0x124));
  amax2(v, idx, ROR_F(v, 0x128), ROR_I(idx, 0x128));
  amax2(v, idx, i2f(__builtin_amdgcn_ds_swizzle(f2i(v), 0x401f)),
        __builtin_amdgcn_ds_swizzle(idx, 0x401f));
#if __has_builtin(__builtin_amdgcn_permlane32_swap)
  {
    auto rv = __builtin_amdgcn_permlane32_swap((unsigned)f2i(v), (unsigned)f2i(v), false, false);
    auto ri = __builtin_amdgcn_permlane32_swap((unsigned)idx, (unsigned)idx, false, false);
    amax2(v, idx, i2f((int)rv[0]), (int)ri[0]);
    amax2(v, idx, i2f((int)rv[1]), (int)ri[1]);
  }
#else
  amax2(v, idx, __shfl_xor(v, 32, 64), __shfl_xor(idx, 32, 64));
#endif
}

// 512 threads = 8 waves/block; 2 blocks/CU (LDS 80.4KB x2 = 160.8KB <= 163.8KB).
// __launch_bounds__(512,2) => VGPR cap 256/2 = 128. R2's structure allocates
// 124 — 4 regs of headroom. R3/R4 showed the IC<>/lambda dual-instantiation
// structure tips past 128 and spills (408MB FETCH / 800MB WRITE scratch) —
// keep the single inline body + runtime-g loop. The ONLY change vs R2 here is
// the Phase-B p-pair repack (W2T layout), which SHRINKS the w live set.
__global__ __launch_bounds__(512, 2) void match_kernel(
    const float* __restrict__ s1, const float* __restrict__ s2,
    const float* __restrict__ w1, const float* __restrict__ w2,
    const float* __restrict__ w3, const float* __restrict__ w4,
    const float* __restrict__ w5, const float* __restrict__ w6,
    const float* __restrict__ w7, const float* __restrict__ w8,
    float* __restrict__ out)
{
  const int dir  = blockIdx.x & 1;
  const int b    = blockIdx.x >> 1;
  const int doff = dir * DD;
  const int tid  = threadIdx.x;
  const int lane = tid & 63;
  const int wv   = tid >> 6;

  const float* wfull = dir ? w2 : w1;
  const float* wmax  = dir ? w4 : w3;
  const float* wmean = dir ? w6 : w5;
  const float* watt2 = dir ? w8 : w7;   // fwd: max-att (w7); bwd: mean-att (w8)

  // s2 in d-chunked layout: d = 4c+k. j-stride = 16B (b128-able, conflict-free
  // lane-over-j); chunk stride = 404 dwords == 20 mod 32 (2-way free in phase D).
  __shared__ __align__(16) float S2V[DC][TT + 1][4];
  __shared__ __align__(16) float W2SQ[PP][DD];       // p-row layout: norm passes
  __shared__ __align__(16) float W2T[DC][4][PP];     // d-major: Phase-B v2f p-pairs
  __shared__ float N2PI[TT];
  __shared__ float N2WI[TT][11];        // padded: (11j+p)%32 -> 2-way free
  // Wave-private regions (wave owns rows [wv*4, wv*4+4)): no barriers needed.
  __shared__ __align__(16) float S1R[4 * NW][DD];
  __shared__ __align__(16) float CROW[4 * NW][DD];
  __shared__ float N1PI[4 * NW];
  __shared__ float N1WI[4 * NW][PP];
  __shared__ int   ARGJ[4 * NW];

  // ---- Phase 1: load s2 tile (d-chunked) + maxpool w^2 in BOTH layouts ----
  for (int idx = tid; idx < TT * DD; idx += 512) {
    int j = idx / DD, d = idx - j * DD;
    S2V[d >> 2][j][d & 3] = s2[(j * BBATCH + b) * (2 * DD) + doff + d];
  }
  for (int idx = tid; idx < PP * DD; idx += 512) {
    int p = idx / DD, d = idx - p * DD;
    float v = wmax[idx];
    float v2 = v * v;
    W2SQ[p][d] = v2;
    W2T[d >> 2][d & 3][p] = v2;
  }
  __syncthreads();

  // ---- Phase 2: s2 norms (plain + weighted rsqrt), float4 reads ----
  for (int task = tid; task < TT + TT * PP; task += 512) {
    if (task < TT) {
      int j = task;
      float a = 0.f;
      for (int c = 0; c < DC; ++c) {
        v4f f = *(const v4f*)&S2V[c][j][0];
#pragma unroll
        for (int k = 0; k < 4; ++k) a = fmaf(f[k], f[k], a);
      }
      N2PI[j] = 1.0f / sqrtf(fmaxf(a, FEPS));   // feeds argmax-sensitive cos
    } else {
      int q = task - TT; int j = q / PP, p = q - j * PP;
      float a = 0.f;
      for (int c = 0; c < DC; ++c) {
        v4f f = *(const v4f*)&S2V[c][j][0];
        v4f w = *(const v4f*)&W2SQ[p][4 * c];
#pragma unroll
        for (int k = 0; k < 4; ++k) a = fmaf(f[k] * f[k], w[k], a);
      }
      N2WI[j][p] = rsqrtf(fmaxf(a, FEPS));
    }
  }
  __syncthreads();
  // ---- After this point: ZERO barriers. Remaining LDS state is read-only
  // (S2V/W2SQ/W2T/N2*) or wave-private (S1R/CROW/N1*/ARGJ).

  const int  j0   = lane;
  const int  j1   = 64 + lane;
  const bool act1 = (j1 < TT);
  const int  j1c  = act1 ? j1 : (TT - 1);
  const bool actd = (64 + lane) < DD;
  const int  d1   = actd ? (64 + lane) : (DD - 1);
  const int  c0i  = lane >> 2, k0 = lane & 3;      // phase-D d0 = lane
  const int  c1i  = d1 >> 2,   k1 = d1 & 3;        // phase-D d1

  const int sl = wv * 4;

  // ---- 25 row-groups strided over 8 waves (R2 schedule — single body) ----
  for (int g = wv; g < 25; g += NW) {
    const int i0 = g * 4;          // rows i0..i0+3, always < 100

    // wave-private S1R staging: 4 rows x 25 float4 chunks
    for (int q = lane; q < 4 * DC; q += 64) {
      int rr = q / DC, c = q - rr * DC;
      *(v4f*)&S1R[sl + rr][4 * c] =
          *(const v4f*)&s1[((i0 + rr) * BBATCH + b) * (2 * DD) + doff + 4 * c];
    }

    // wave-private s1 norms: 4 rows x (1 plain + 10 weighted) = 44 lane-tasks
    if (lane < 4 * 11) {
      int rr = lane / 11, q = lane - rr * 11;
      if (q == 0) {
        float a = 0.f;
        for (int c = 0; c < DC; ++c) {
          v4f f = *(const v4f*)&S1R[sl + rr][4 * c];
#pragma unroll
          for (int k = 0; k < 4; ++k) a = fmaf(f[k], f[k], a);
        }
        N1PI[sl + rr] = 1.0f / sqrtf(fmaxf(a, FEPS));
      } else {
        int p = q - 1;
        float a = 0.f;
        for (int c = 0; c < DC; ++c) {
          v4f f = *(const v4f*)&S1R[sl + rr][4 * c];
          v4f w = *(const v4f*)&W2SQ[p][4 * c];
#pragma unroll
          for (int k = 0; k < 4; ++k) a = fmaf(f[k] * f[k], w[k], a);
        }
        N1WI[sl + rr][p] = rsqrtf(fmaxf(a, FEPS));
      }
    }

    float rs[4] = {0, 0, 0, 0};
    v2f attp[4] = {{0, 0}, {0, 0}, {0, 0}, {0, 0}};

    // ---- Phase B: scalar dot (j0,j1); maxpool FMAs packed over p-pairs.
    // W2T p-major loads: p-pairs are aligned v2f (and v2f halves of a v4f are
    // free register aliases) -> ZERO w-splat movs (was 20 movs per (c,k,r)).
    // Per-accumulator operation sequence identical to R2 -> bit-exact.
    float dot0[4] = {0, 0, 0, 0};
    float dot1[4] = {0, 0, 0, 0};
    v2f wap[4][2][5];                   // [row][j0/j1][p-pair] = 80 VGPRs (floor)
#pragma unroll
    for (int r = 0; r < 4; ++r)
#pragma unroll
      for (int pp = 0; pp < 5; ++pp) {
        wap[r][0][pp] = (v2f){0.f, 0.f};
        wap[r][1][pp] = (v2f){0.f, 0.f};
      }

    for (int c = 0; c < DC; ++c) {
      v4f s2a4 = *(const v4f*)&S2V[c][j0][0];
      v4f s2b4 = *(const v4f*)&S2V[c][j1c][0];
      v4f s1v[4];
#pragma unroll
      for (int r = 0; r < 4; ++r) s1v[r] = *(const v4f*)&S1R[sl + r][4 * c];
#pragma unroll
      for (int k = 0; k < 4; ++k) {
        v4f wA = *(const v4f*)&W2T[c][k][0];   // p0..3
        v4f wB = *(const v4f*)&W2T[c][k][4];   // p4..7
        v2f wp4 = *(const v2f*)&W2T[c][k][8];  // p8..9
        v2f wp0 = __builtin_shufflevector(wA, wA, 0, 1);   // free (reg alias)
        v2f wp1 = __builtin_shufflevector(wA, wA, 2, 3);
        v2f wp2 = __builtin_shufflevector(wB, wB, 0, 1);
        v2f wp3 = __builtin_shufflevector(wB, wB, 2, 3);
#pragma unroll
        for (int r = 0; r < 4; ++r) {
          float ta0 = s1v[r][k] * s2a4[k];     // v_mul_f32
          float ta1 = s1v[r][k] * s2b4[k];
          dot0[r] += ta0;                      // same order as R2's pk .x/.y lanes
          dot1[r] += ta1;
          v2f t0; t0.x = ta0; t0.y = ta0;      // 2 movs
          v2f t1; t1.x = ta1; t1.y = ta1;      // 2 movs
          wap[r][0][0] = __builtin_elementwise_fma(t0, wp0, wap[r][0][0]);  // v_pk_fma
          wap[r][0][1] = __builtin_elementwise_fma(t0, wp1, wap[r][0][1]);
          wap[r][0][2] = __builtin_elementwise_fma(t0, wp2, wap[r][0][2]);
          wap[r][0][3] = __builtin_elementwise_fma(t0, wp3, wap[r][0][3]);
          wap[r][0][4] = __builtin_elementwise_fma(t0, wp4, wap[r][0][4]);
          wap[r][1][0] = __builtin_elementwise_fma(t1, wp0, wap[r][1][0]);
          wap[r][1][1] = __builtin_elementwise_fma(t1, wp1, wap[r][1][1]);
          wap[r][1][2] = __builtin_elementwise_fma(t1, wp2, wap[r][1][2]);
          wap[r][1][3] = __builtin_elementwise_fma(t1, wp3, wap[r][1][3]);
          wap[r][1][4] = __builtin_elementwise_fma(t1, wp4, wap[r][1][4]);
        }
      }
    }

    // ---- Phase C: cos rows, rowsum, argmax, maxpool (DPP/permlane reductions) ----
#pragma unroll
    for (int r = 0; r < 4; ++r) {
      float n1pi_r = N1PI[sl + r];
      float c0 = dot0[r] * (n1pi_r * N2PI[j0]);
      float c1 = dot1[r] * (n1pi_r * N2PI[j1c]);
      CROW[sl + r][j0] = c0;
      if (act1) CROW[sl + r][j1] = c1;
      rs[r] = wave_sum(c0 + (act1 ? c1 : 0.f));

      float mv = c0; int mi = j0;
      if (act1 && (c1 > mv)) { mv = c1; mi = j1; }
      wave_argmax(mv, mi);
      if (lane == 0) ARGJ[sl + r] = mi;

#pragma unroll
      for (int p = 0; p < PP; ++p) {
        float a0 = (p & 1) ? wap[r][0][p >> 1].y : wap[r][0][p >> 1].x;
        float a1 = (p & 1) ? wap[r][1][p >> 1].y : wap[r][1][p >> 1].x;
        float v0 = a0 * N2WI[j0][p];
        float v1 = act1 ? a1 * N2WI[j1c][p] : -3.4e38f;
        float m = wave_max(fmaxf(v0, v1));
        if (lane == 0) {
          out[((i0 + r) * BBATCH + b) * OC + 20 + dir * PP + p] = m * N1WI[sl + r][p];
        }
      }
    }

    // ---- Phase D: mean-att accumulation, packed (d0,d1); reads own CROW rows ----
    for (int j = 0; j < TT; ++j) {
      v2f s2ab; s2ab.x = S2V[c0i][j][k0]; s2ab.y = S2V[c1i][j][k1];
#pragma unroll
      for (int r = 0; r < 4; ++r) {
        float cv = CROW[sl + r][j];
        v2f cc; cc.x = cv; cc.y = cv;
        attp[r] = __builtin_elementwise_fma(cc, s2ab, attp[r]);
      }
    }

    // overwrite own CROW rows with att rows (same-wave ordering suffices)
#pragma unroll
    for (int r = 0; r < 4; ++r) {
      float inv = 1.0f / (rs[r] + FEPS);
      CROW[sl + r][lane] = attp[r].x * inv;
      if (actd) CROW[sl + r][64 + lane] = attp[r].y * inv;
    }

    // ---- Phase E: epilogue: 120 tasks = 4 rows x {full, mean-att, att2} x 10 p
    for (int tk = lane; tk < 120; tk += 64) {
      int r = tk / 30;
      int q = tk - r * 30;
      int set = q / PP;
      int p = q - set * PP;
      const float* wrow = (set == 0 ? wfull : (set == 1 ? wmean : watt2)) + p * DD;
      // reference quirk: s2.reshape(-1,D)[argmax] == s2f[0, argmax, :] (fwd only)
      const float* gat = s2 + ARGJ[sl + r] * (2 * DD);
      float num = 0.f, nx = 0.f, ny = 0.f;
      for (int c = 0; c < DC; ++c) {
        v4f x4 = *(const v4f*)&S1R[sl + r][4 * c];
        v4f y4;
        if (set == 0)                     y4 = *(const v4f*)&S2V[c][TT - 1][0];
        else if (set == 1 || dir == 1)    y4 = *(const v4f*)&CROW[sl + r][4 * c];
        else                              y4 = *(const v4f*)&gat[4 * c];
        v4f w4 = *(const v4f*)&wrow[4 * c];
#pragma unroll
        for (int k = 0; k < 4; ++k) {
          float w2v = w4[k] * w4[k];
          num = fmaf(x4[k] * y4[k], w2v, num);
          nx  = fmaf(x4[k] * x4[k], w2v, nx);
          ny  = fmaf(y4[k] * y4[k], w2v, ny);
        }
      }
      float cres = num * rsqrtf(fmaxf(nx, FEPS)) * rsqrtf(fmaxf(ny, FEPS));
      int ch = (set == 0 ? 0 : (set == 1 ? 40 : 60)) + dir * PP + p;
      out[((i0 + r) * BBATCH + b) * OC + ch] = cres;
    }
  }
}

extern "C" void kernel_launch(void* const* d_in, const int* in_sizes, int n_in,
                              void* d_out, int out_size, void* d_ws, size_t ws_size,
                              hipStream_t stream) {
  const float* s1 = (const float*)d_in[0];
  const float* s2 = (const float*)d_in[1];
  match_kernel<<<dim3(512), dim3(512), 0, stream>>>(
      s1, s2,
      (const float*)d_in[2], (const float*)d_in[3],
      (const float*)d_in[4], (const float*)d_in[5],
      (const float*)d_in[6], (const float*)d_in[7],
      (const float*)d_in[8], (const float*)d_in[9],
      (float*)d_out);
}

// Round 6
// 409.263 us; speedup vs baseline: 1.9766x; 1.0213x over previous
//
#include <hip/hip_runtime.h>

#define TT 100
#define DD 100
#define DC 25      // DD/4
#define PP 10
#define BBATCH 256
#define OC 80
#define NW 8       // waves per block (512 threads)
#define NR 2       // rows per wave per group (register tile)

typedef float v2f __attribute__((ext_vector_type(2)));
typedef float v4f __attribute__((ext_vector_type(4)));

static constexpr float FEPS = 1e-6f;

__device__ __forceinline__ int   f2i(float x) { return __builtin_bit_cast(int, x); }
__device__ __forceinline__ float i2f(int x)   { return __builtin_bit_cast(float, x); }

// DPP row_ror:n within 16-lane rows — VALU pipe, no LDS traffic.
#define ROR_F(v, ctrl) i2f(__builtin_amdgcn_update_dpp(0, f2i(v), (ctrl), 0xf, 0xf, false))
#define ROR_I(v, ctrl) __builtin_amdgcn_update_dpp(0, (v), (ctrl), 0xf, 0xf, false)

__device__ __forceinline__ v2f xswap32_f(float v) {
#if __has_builtin(__builtin_amdgcn_permlane32_swap)
  auto pr = __builtin_amdgcn_permlane32_swap((unsigned)f2i(v), (unsigned)f2i(v), false, false);
  v2f r; r.x = i2f((int)pr[0]); r.y = i2f((int)pr[1]);
  return r;
#else
  v2f r; r.x = v; r.y = __shfl_xor(v, 32, 64);
  return r;
#endif
}

__device__ __forceinline__ float wave_sum(float v) {
  v += ROR_F(v, 0x121);
  v += ROR_F(v, 0x122);
  v += ROR_F(v, 0x124);
  v += ROR_F(v, 0x128);
  v += i2f(__builtin_amdgcn_ds_swizzle(f2i(v), 0x401f));   // lane ^ 16
  v2f s = xswap32_f(v);                                    // lane ^ 32
  return s.x + s.y;
}

__device__ __forceinline__ float wave_max(float v) {
  v = fmaxf(v, ROR_F(v, 0x121));
  v = fmaxf(v, ROR_F(v, 0x122));
  v = fmaxf(v, ROR_F(v, 0x124));
  v = fmaxf(v, ROR_F(v, 0x128));
  v = fmaxf(v, i2f(__builtin_amdgcn_ds_swizzle(f2i(v), 0x401f)));
  v2f s = xswap32_f(v);
  return fmaxf(s.x, s.y);
}

__device__ __forceinline__ void amax2(float& v, int& i, float ov, int oi) {
  if (ov > v || (ov == v && oi < i)) { v = ov; i = oi; }
}

__device__ __forceinline__ void wave_argmax(float& v, int& idx) {
  amax2(v, idx, ROR_F(v, 0x121), ROR_I(idx, 0x121));
  amax2(v, idx, ROR_F(v, 0x122), ROR_I(idx, 0x122));
  amax2(v, idx, ROR_F(v, 0x124), ROR_I(idx, 0x124));
  amax2(v, idx, ROR_F(v, 0x128), ROR_I(idx, 0x128));
  amax2(v, idx, i2f(__builtin_amdgcn_ds_swizzle(f2i(v), 0x401f)),
        __builtin_amdgcn_ds_swizzle(idx, 0x401f));
#if __has_builtin(__builtin_amdgcn_permlane32_swap)
  {
    auto rv = __builtin_amdgcn_permlane32_swap((unsigned)f2i(v), (unsigned)f2i(v), false, false);
    auto ri = __builtin_amdgcn_permlane32_swap((unsigned)idx, (unsigned)idx, false, false);
    amax2(v, idx, i2f((int)rv[0]), (int)ri[0]);
    amax2(v, idx, i2f((int)rv[1]), (int)ri[1]);
  }
#else
  amax2(v, idx, __shfl_xor(v, 32, 64), __shfl_xor(idx, 32, 64));
#endif
}

// NR=2 probe: VGPR residency theory. R0/R1/R2/R5 occupancy pattern (22/44/20/20
// at VGPR 120(4-wave blk)/64/124/112) suggests a 32-reg allocation granule:
// 112 and 124 both round to 128; 4 waves/SIMD x 128 = 512 = whole pool -> any
// reservation blocks the 2nd block -> 1 blk/CU. Target VGPR <= 96 strictly
// (wap[2][2][5]=40 acc floor vs 80). Keep single inline body (R3/R4: lambda
// dual-instantiation spills) and __launch_bounds__(512,2) (cap 128).
__global__ __launch_bounds__(512, 2) void match_kernel(
    const float* __restrict__ s1, const float* __restrict__ s2,
    const float* __restrict__ w1, const float* __restrict__ w2,
    const float* __restrict__ w3, const float* __restrict__ w4,
    const float* __restrict__ w5, const float* __restrict__ w6,
    const float* __restrict__ w7, const float* __restrict__ w8,
    float* __restrict__ out)
{
  const int dir  = blockIdx.x & 1;
  const int b    = blockIdx.x >> 1;
  const int doff = dir * DD;
  const int tid  = threadIdx.x;
  const int lane = tid & 63;
  const int wv   = tid >> 6;

  const float* wfull = dir ? w2 : w1;
  const float* wmax  = dir ? w4 : w3;
  const float* wmean = dir ? w6 : w5;
  const float* watt2 = dir ? w8 : w7;   // fwd: max-att (w7); bwd: mean-att (w8)

  // s2 in d-chunked layout: d = 4c+k. j-stride = 16B (b128-able, conflict-free
  // lane-over-j); chunk stride = 404 dwords == 20 mod 32 (2-way free in phase D).
  __shared__ __align__(16) float S2V[DC][TT + 1][4];
  __shared__ __align__(16) float W2SQ[PP][DD];       // p-row layout: norm passes
  __shared__ __align__(16) float W2T[DC][4][PP];     // d-major: Phase-B v2f p-pairs
  __shared__ float N2PI[TT];
  __shared__ float N2WI[TT][11];        // padded: (11j+p)%32 -> 2-way free
  // Wave-private regions (wave owns rows [wv*NR, wv*NR+NR)): no barriers needed.
  __shared__ __align__(16) float S1R[NR * NW][DD];
  __shared__ __align__(16) float CROW[NR * NW][DD];
  __shared__ float N1PI[NR * NW];
  __shared__ float N1WI[NR * NW][PP];
  __shared__ int   ARGJ[NR * NW];

  // ---- Phase 1: load s2 tile (d-chunked) + maxpool w^2 in BOTH layouts ----
  for (int idx = tid; idx < TT * DD; idx += 512) {
    int j = idx / DD, d = idx - j * DD;
    S2V[d >> 2][j][d & 3] = s2[(j * BBATCH + b) * (2 * DD) + doff + d];
  }
  for (int idx = tid; idx < PP * DD; idx += 512) {
    int p = idx / DD, d = idx - p * DD;
    float v = wmax[idx];
    float v2 = v * v;
    W2SQ[p][d] = v2;
    W2T[d >> 2][d & 3][p] = v2;
  }
  __syncthreads();

  // ---- Phase 2: s2 norms (plain + weighted rsqrt), float4 reads ----
  for (int task = tid; task < TT + TT * PP; task += 512) {
    if (task < TT) {
      int j = task;
      float a = 0.f;
      for (int c = 0; c < DC; ++c) {
        v4f f = *(const v4f*)&S2V[c][j][0];
#pragma unroll
        for (int k = 0; k < 4; ++k) a = fmaf(f[k], f[k], a);
      }
      N2PI[j] = 1.0f / sqrtf(fmaxf(a, FEPS));   // feeds argmax-sensitive cos
    } else {
      int q = task - TT; int j = q / PP, p = q - j * PP;
      float a = 0.f;
      for (int c = 0; c < DC; ++c) {
        v4f f = *(const v4f*)&S2V[c][j][0];
        v4f w = *(const v4f*)&W2SQ[p][4 * c];
#pragma unroll
        for (int k = 0; k < 4; ++k) a = fmaf(f[k] * f[k], w[k], a);
      }
      N2WI[j][p] = rsqrtf(fmaxf(a, FEPS));
    }
  }
  __syncthreads();
  // ---- After this point: ZERO barriers. Remaining LDS state is read-only
  // (S2V/W2SQ/W2T/N2*) or wave-private (S1R/CROW/N1*/ARGJ).

  const int  j0   = lane;
  const int  j1   = 64 + lane;
  const bool act1 = (j1 < TT);
  const int  j1c  = act1 ? j1 : (TT - 1);
  const bool actd = (64 + lane) < DD;
  const int  d1   = actd ? (64 + lane) : (DD - 1);
  const int  c0i  = lane >> 2, k0 = lane & 3;      // phase-D d0 = lane
  const int  c1i  = d1 >> 2,   k1 = d1 & 3;        // phase-D d1

  const int sl = wv * NR;

  // ---- 50 row-groups (2 rows each) strided over 8 waves: waves get 7 or 6
  // groups (12% imbalance vs 28% with 4-row groups). ----
  for (int g = wv; g < 50; g += NW) {
    const int i0 = g * NR;         // rows i0..i0+1, always < 100

    // wave-private S1R staging: 2 rows x 25 float4 chunks = 50 tasks
    if (lane < NR * DC) {
      int rr = lane / DC, c = lane - rr * DC;
      *(v4f*)&S1R[sl + rr][4 * c] =
          *(const v4f*)&s1[((i0 + rr) * BBATCH + b) * (2 * DD) + doff + 4 * c];
    }

    // wave-private s1 norms: 2 rows x (1 plain + 10 weighted) = 22 lane-tasks
    if (lane < NR * 11) {
      int rr = lane / 11, q = lane - rr * 11;
      if (q == 0) {
        float a = 0.f;
        for (int c = 0; c < DC; ++c) {
          v4f f = *(const v4f*)&S1R[sl + rr][4 * c];
#pragma unroll
          for (int k = 0; k < 4; ++k) a = fmaf(f[k], f[k], a);
        }
        N1PI[sl + rr] = 1.0f / sqrtf(fmaxf(a, FEPS));
      } else {
        int p = q - 1;
        float a = 0.f;
        for (int c = 0; c < DC; ++c) {
          v4f f = *(const v4f*)&S1R[sl + rr][4 * c];
          v4f w = *(const v4f*)&W2SQ[p][4 * c];
#pragma unroll
          for (int k = 0; k < 4; ++k) a = fmaf(f[k] * f[k], w[k], a);
        }
        N1WI[sl + rr][p] = rsqrtf(fmaxf(a, FEPS));
      }
    }

    float rs[NR] = {0, 0};
    v2f attp[NR] = {{0, 0}, {0, 0}};

    // ---- Phase B: scalar dot (j0,j1); maxpool FMAs packed over p-pairs ----
    // (accumulation order per (j,p) accumulator identical to R2/R5 -> bit-exact)
    float dot0[NR] = {0, 0};
    float dot1[NR] = {0, 0};
    v2f wap[NR][2][5];                  // [row][j0/j1][p-pair] = 40 VGPRs
#pragma unroll
    for (int r = 0; r < NR; ++r)
#pragma unroll
      for (int pp = 0; pp < 5; ++pp) {
        wap[r][0][pp] = (v2f){0.f, 0.f};
        wap[r][1][pp] = (v2f){0.f, 0.f};
      }

    for (int c = 0; c < DC; ++c) {
      v4f s2a4 = *(const v4f*)&S2V[c][j0][0];
      v4f s2b4 = *(const v4f*)&S2V[c][j1c][0];
      v4f s1v[NR];
#pragma unroll
      for (int r = 0; r < NR; ++r) s1v[r] = *(const v4f*)&S1R[sl + r][4 * c];
#pragma unroll
      for (int k = 0; k < 4; ++k) {
        v4f wA = *(const v4f*)&W2T[c][k][0];   // p0..3
        v4f wB = *(const v4f*)&W2T[c][k][4];   // p4..7
        v2f wp4 = *(const v2f*)&W2T[c][k][8];  // p8..9
        v2f wp0 = __builtin_shufflevector(wA, wA, 0, 1);
        v2f wp1 = __builtin_shufflevector(wA, wA, 2, 3);
        v2f wp2 = __builtin_shufflevector(wB, wB, 0, 1);
        v2f wp3 = __builtin_shufflevector(wB, wB, 2, 3);
#pragma unroll
        for (int r = 0; r < NR; ++r) {
          float ta0 = s1v[r][k] * s2a4[k];
          float ta1 = s1v[r][k] * s2b4[k];
          dot0[r] += ta0;
          dot1[r] += ta1;
          v2f t0; t0.x = ta0; t0.y = ta0;
          v2f t1; t1.x = ta1; t1.y = ta1;
          wap[r][0][0] = __builtin_elementwise_fma(t0, wp0, wap[r][0][0]);
          wap[r][0][1] = __builtin_elementwise_fma(t0, wp1, wap[r][0][1]);
          wap[r][0][2] = __builtin_elementwise_fma(t0, wp2, wap[r][0][2]);
          wap[r][0][3] = __builtin_elementwise_fma(t0, wp3, wap[r][0][3]);
          wap[r][0][4] = __builtin_elementwise_fma(t0, wp4, wap[r][0][4]);
          wap[r][1][0] = __builtin_elementwise_fma(t1, wp0, wap[r][1][0]);
          wap[r][1][1] = __builtin_elementwise_fma(t1, wp1, wap[r][1][1]);
          wap[r][1][2] = __builtin_elementwise_fma(t1, wp2, wap[r][1][2]);
          wap[r][1][3] = __builtin_elementwise_fma(t1, wp3, wap[r][1][3]);
          wap[r][1][4] = __builtin_elementwise_fma(t1, wp4, wap[r][1][4]);
        }
      }
    }

    // ---- Phase C: cos rows, rowsum, argmax, maxpool (DPP/permlane reductions) ----
#pragma unroll
    for (int r = 0; r < NR; ++r) {
      float n1pi_r = N1PI[sl + r];
      float c0 = dot0[r] * (n1pi_r * N2PI[j0]);
      float c1 = dot1[r] * (n1pi_r * N2PI[j1c]);
      CROW[sl + r][j0] = c0;
      if (act1) CROW[sl + r][j1] = c1;
      rs[r] = wave_sum(c0 + (act1 ? c1 : 0.f));

      float mv = c0; int mi = j0;
      if (act1 && (c1 > mv)) { mv = c1; mi = j1; }
      wave_argmax(mv, mi);
      if (lane == 0) ARGJ[sl + r] = mi;

#pragma unroll
      for (int p = 0; p < PP; ++p) {
        float a0 = (p & 1) ? wap[r][0][p >> 1].y : wap[r][0][p >> 1].x;
        float a1 = (p & 1) ? wap[r][1][p >> 1].y : wap[r][1][p >> 1].x;
        float v0 = a0 * N2WI[j0][p];
        float v1 = act1 ? a1 * N2WI[j1c][p] : -3.4e38f;
        float m = wave_max(fmaxf(v0, v1));
        if (lane == 0) {
          out[((i0 + r) * BBATCH + b) * OC + 20 + dir * PP + p] = m * N1WI[sl + r][p];
        }
      }
    }

    // ---- Phase D: mean-att accumulation, packed (d0,d1); reads own CROW rows ----
    for (int j = 0; j < TT; ++j) {
      v2f s2ab; s2ab.x = S2V[c0i][j][k0]; s2ab.y = S2V[c1i][j][k1];
#pragma unroll
      for (int r = 0; r < NR; ++r) {
        float cv = CROW[sl + r][j];
        v2f cc; cc.x = cv; cc.y = cv;
        attp[r] = __builtin_elementwise_fma(cc, s2ab, attp[r]);
      }
    }

    // overwrite own CROW rows with att rows (same-wave ordering suffices)
#pragma unroll
    for (int r = 0; r < NR; ++r) {
      float inv = 1.0f / (rs[r] + FEPS);
      CROW[sl + r][lane] = attp[r].x * inv;
      if (actd) CROW[sl + r][64 + lane] = attp[r].y * inv;
    }

    // ---- Phase E: epilogue: 60 tasks = 2 rows x {full, mean-att, att2} x 10 p
    if (lane < NR * 30) {
      int tk = lane;
      int r = tk / 30;
      int q = tk - r * 30;
      int set = q / PP;
      int p = q - set * PP;
      const float* wrow = (set == 0 ? wfull : (set == 1 ? wmean : watt2)) + p * DD;
      // reference quirk: s2.reshape(-1,D)[argmax] == s2f[0, argmax, :] (fwd only)
      const float* gat = s2 + ARGJ[sl + r] * (2 * DD);
      float num = 0.f, nx = 0.f, ny = 0.f;
      for (int c = 0; c < DC; ++c) {
        v4f x4 = *(const v4f*)&S1R[sl + r][4 * c];
        v4f y4;
        if (set == 0)                     y4 = *(const v4f*)&S2V[c][TT - 1][0];
        else if (set == 1 || dir == 1)    y4 = *(const v4f*)&CROW[sl + r][4 * c];
        else                              y4 = *(const v4f*)&gat[4 * c];
        v4f w4 = *(const v4f*)&wrow[4 * c];
#pragma unroll
        for (int k = 0; k < 4; ++k) {
          float w2v = w4[k] * w4[k];
          num = fmaf(x4[k] * y4[k], w2v, num);
          nx  = fmaf(x4[k] * x4[k], w2v, nx);
          ny  = fmaf(y4[k] * y4[k], w2v, ny);
        }
      }
      float cres = num * rsqrtf(fmaxf(nx, FEPS)) * rsqrtf(fmaxf(ny, FEPS));
      int ch = (set == 0 ? 0 : (set == 1 ? 40 : 60)) + dir * PP + p;
      out[((i0 + r) * BBATCH + b) * OC + ch] = cres;
    }
  }
}

extern "C" void kernel_launch(void* const* d_in, const int* in_sizes, int n_in,
                              void* d_out, int out_size, void* d_ws, size_t ws_size,
                              hipStream_t stream) {
  const float* s1 = (const float*)d_in[0];
  const float* s2 = (const float*)d_in[1];
  match_kernel<<<dim3(512), dim3(512), 0, stream>>>(
      s1, s2,
      (const float*)d_in[2], (const float*)d_in[3],
      (const float*)d_in[4], (const float*)d_in[5],
      (const float*)d_in[6], (const float*)d_in[7],
      (const float*)d_in[8], (const float*)d_in[9],
      (float*)d_out);
}